// Round 2
// baseline (60.736 us; speedup 1.0000x reference)
//
#include <hip/hip_runtime.h>
#include <hip/hip_bf16.h>

#define NTOK 2048

__device__ __forceinline__ float sigm(float x) { return 1.0f / (1.0f + __expf(-x)); }

// ------------------------------------------------------------------
// Kernel P: dual AdaLN + projections.
// Per block: 8 rows. Computes q (+bq), k, v, sigmoid(g), sigmoid(cond@Wgs+bgs).
// ------------------------------------------------------------------
__global__ __launch_bounds__(256) void proj_kernel(
    const float* __restrict__ act, const float* __restrict__ cond,
    const float* __restrict__ lns_q, const float* __restrict__ Wgate_q,
    const float* __restrict__ bgate_q, const float* __restrict__ Wskip_q,
    const float* __restrict__ lns_k, const float* __restrict__ Wgate_k,
    const float* __restrict__ bgate_k, const float* __restrict__ Wskip_k,
    const float* __restrict__ Wq, const float* __restrict__ bq,
    const float* __restrict__ Wk, const float* __restrict__ Wv,
    const float* __restrict__ Wg, const float* __restrict__ Wgs,
    const float* __restrict__ bgs,
    float* __restrict__ q_ws, float* __restrict__ k_ws, float* __restrict__ v_ws,
    float* __restrict__ gsig_ws, float* __restrict__ gs_ws)
{
  __shared__ float xn[8][128], snq[8][128], snk[8][128], cnd[8][128];
  __shared__ float aq[8][128], ak[8][128];
  __shared__ float wt[16384];
  const int tid = threadIdx.x;
  const int row0 = blockIdx.x * 8;
  const int mr = tid >> 5;          // row 0..7
  const int n0 = (tid & 31) << 2;   // col base 0..124

  // ---- LayerNorms ----
  {
    const size_t base = (size_t)(row0 + mr) * 128 + n0;
    float4 xv4 = *reinterpret_cast<const float4*>(act + base);
    float4 cv4 = *reinterpret_cast<const float4*>(cond + base);
    float xv[4] = {xv4.x, xv4.y, xv4.z, xv4.w};
    float cv[4] = {cv4.x, cv4.y, cv4.z, cv4.w};
    float sx = 0, sxx = 0, sc = 0, scc = 0;
#pragma unroll
    for (int i = 0; i < 4; ++i) {
      sx += xv[i]; sxx += xv[i] * xv[i];
      sc += cv[i]; scc += cv[i] * cv[i];
    }
#pragma unroll
    for (int m = 1; m < 32; m <<= 1) {
      sx += __shfl_xor(sx, m, 32); sxx += __shfl_xor(sxx, m, 32);
      sc += __shfl_xor(sc, m, 32); scc += __shfl_xor(scc, m, 32);
    }
    const float mxm = sx * (1.f / 128.f), vx = sxx * (1.f / 128.f) - mxm * mxm;
    const float mcm = sc * (1.f / 128.f), vc = scc * (1.f / 128.f) - mcm * mcm;
    const float rx = rsqrtf(vx + 1e-5f), rc = rsqrtf(vc + 1e-5f);
    float4 lq = *reinterpret_cast<const float4*>(lns_q + n0);
    float4 lk = *reinterpret_cast<const float4*>(lns_k + n0);
    float lqa[4] = {lq.x, lq.y, lq.z, lq.w};
    float lka[4] = {lk.x, lk.y, lk.z, lk.w};
#pragma unroll
    for (int i = 0; i < 4; ++i) {
      float sn = (cv[i] - mcm) * rc;
      xn[mr][n0 + i] = (xv[i] - mxm) * rx;
      snq[mr][n0 + i] = sn * lqa[i];
      snk[mr][n0 + i] = sn * lka[i];
      cnd[mr][n0 + i] = cv[i];
    }
  }

  auto loadw = [&](const float* W) {
    const float4* s = reinterpret_cast<const float4*>(W);
    float4* d = reinterpret_cast<float4*>(wt);
#pragma unroll
    for (int i = 0; i < 16; ++i) d[tid + (i << 8)] = s[tid + (i << 8)];
  };
  float acc0[4], acc1[4];
  auto mm = [&](const float (*A)[128], float* acc) {
    acc[0] = acc[1] = acc[2] = acc[3] = 0.f;
#pragma unroll 4
    for (int kk = 0; kk < 128; ++kk) {
      float a = A[mr][kk];
      float4 w = *reinterpret_cast<const float4*>(&wt[kk * 128 + n0]);
      acc[0] += a * w.x;
      acc[1] += a * w.y;
      acc[2] += a * w.z;
      acc[3] += a * w.w;
    }
  };
  auto writeout = [&](float* dst, const float* acc) {
    float4 o = make_float4(acc[0], acc[1], acc[2], acc[3]);
    *reinterpret_cast<float4*>(dst + (size_t)(row0 + mr) * 128 + n0) = o;
  };

  // a_q
  loadw(Wgate_q);
  __syncthreads();
  mm(snq, acc0);
  __syncthreads();
  loadw(Wskip_q);
  __syncthreads();
  mm(snq, acc1);
  {
    float4 ub = *reinterpret_cast<const float4*>(bgate_q + n0);
    float bb[4] = {ub.x, ub.y, ub.z, ub.w};
#pragma unroll
    for (int i = 0; i < 4; ++i)
      aq[mr][n0 + i] = sigm(acc0[i] + bb[i]) * xn[mr][n0 + i] + acc1[i];
  }
  __syncthreads();
  // a_k
  loadw(Wgate_k);
  __syncthreads();
  mm(snk, acc0);
  __syncthreads();
  loadw(Wskip_k);
  __syncthreads();
  mm(snk, acc1);
  {
    float4 ub = *reinterpret_cast<const float4*>(bgate_k + n0);
    float bb[4] = {ub.x, ub.y, ub.z, ub.w};
#pragma unroll
    for (int i = 0; i < 4; ++i)
      ak[mr][n0 + i] = sigm(acc0[i] + bb[i]) * xn[mr][n0 + i] + acc1[i];
  }
  __syncthreads();
  // q = a_q@Wq + bq
  loadw(Wq);
  __syncthreads();
  mm(aq, acc0);
  {
    float4 ub = *reinterpret_cast<const float4*>(bq + n0);
    acc0[0] += ub.x; acc0[1] += ub.y; acc0[2] += ub.z; acc0[3] += ub.w;
    writeout(q_ws, acc0);
  }
  __syncthreads();
  // gsig = sigmoid(a_q@Wg)
  loadw(Wg);
  __syncthreads();
  mm(aq, acc0);
#pragma unroll
  for (int i = 0; i < 4; ++i) acc0[i] = sigm(acc0[i]);
  writeout(gsig_ws, acc0);
  __syncthreads();
  // k = a_k@Wk
  loadw(Wk);
  __syncthreads();
  mm(ak, acc0);
  writeout(k_ws, acc0);
  __syncthreads();
  // v = a_k@Wv
  loadw(Wv);
  __syncthreads();
  mm(ak, acc0);
  writeout(v_ws, acc0);
  __syncthreads();
  // gs = sigmoid(cond@Wgs + bgs)
  loadw(Wgs);
  __syncthreads();
  mm(cnd, acc0);
  {
    float4 ub = *reinterpret_cast<const float4*>(bgs + n0);
    float bb[4] = {ub.x, ub.y, ub.z, ub.w};
#pragma unroll
    for (int i = 0; i < 4; ++i) acc0[i] = sigm(acc0[i] + bb[i]);
    writeout(gs_ws, acc0);
  }
}

// ------------------------------------------------------------------
// Kernel Z: windowed pair bias. bias[i][jw][h] = LN(pair[i,j,:])*lnz_w @ Wb
// j out of range -> -1e9 (mask).
// ------------------------------------------------------------------
__global__ __launch_bounds__(256) void bias_kernel(
    const float* __restrict__ pair, const float* __restrict__ lnz_w,
    const float* __restrict__ Wb, float* __restrict__ bias_ws)
{
  __shared__ float lw[16], wb[16][4];
  const int tid = threadIdx.x;
  if (tid < 16) lw[tid] = lnz_w[tid];
  if (tid < 64) wb[tid >> 2][tid & 3] = Wb[tid];
  __syncthreads();
  const int idx = blockIdx.x * 256 + tid;       // 0..262143
  const int i = idx >> 7, jw = idx & 127;
  const int j = ((i >> 5) << 5) - 48 + jw;
  float b0 = -1e9f, b1 = -1e9f, b2 = -1e9f, b3 = -1e9f;
  if (j >= 0 && j < NTOK) {
    const float4* p = reinterpret_cast<const float4*>(pair + ((size_t)i * NTOK + j) * 16);
    float4 z0 = p[0], z1 = p[1], z2 = p[2], z3 = p[3];
    float z[16] = {z0.x, z0.y, z0.z, z0.w, z1.x, z1.y, z1.z, z1.w,
                   z2.x, z2.y, z2.z, z2.w, z3.x, z3.y, z3.z, z3.w};
    float s = 0, ss = 0;
#pragma unroll
    for (int c = 0; c < 16; ++c) { s += z[c]; ss += z[c] * z[c]; }
    const float m = s * (1.f / 16.f), v = ss * (1.f / 16.f) - m * m;
    const float r = rsqrtf(v + 1e-5f);
    b0 = b1 = b2 = b3 = 0.f;
#pragma unroll
    for (int c = 0; c < 16; ++c) {
      float zn = (z[c] - m) * r * lw[c];
      b0 += zn * wb[c][0]; b1 += zn * wb[c][1];
      b2 += zn * wb[c][2]; b3 += zn * wb[c][3];
    }
  }
  reinterpret_cast<float4*>(bias_ws)[idx] = make_float4(b0, b1, b2, b3);
}

// ------------------------------------------------------------------
// Kernel A: local attention per (query-block, head). Window = 128 keys.
// ------------------------------------------------------------------
__global__ __launch_bounds__(256) void attn_kernel(
    const float* __restrict__ q_ws, const float* __restrict__ k_ws,
    const float* __restrict__ v_ws, const float* __restrict__ gsig_ws,
    const float* __restrict__ bias_ws, float* __restrict__ o_ws)
{
  __shared__ float kb[128][32];   // XOR-swizzled columns
  __shared__ float vb[128][32];
  __shared__ float qb[32][36];    // padded
  __shared__ float sb[128][33];   // probs, transposed [jw][qi], padded
  const int tid = threadIdx.x;
  const int h = blockIdx.x & 3;
  const int b = blockIdx.x >> 2;
  const int j0 = b * 32 - 48;
  const int qi = tid >> 3;        // 0..31
  const int g8 = tid & 7;         // 0..7
  const int c4 = g8 << 2;

  // load K/V window (invalid rows -> 0) and Q
#pragma unroll
  for (int it = 0; it < 4; ++it) {
    int jw = qi + (it << 5);
    int j = j0 + jw;
    float4 kv = make_float4(0, 0, 0, 0), vv = make_float4(0, 0, 0, 0);
    if (j >= 0 && j < NTOK) {
      size_t base = ((size_t)j * 4 + h) * 32 + c4;
      kv = *reinterpret_cast<const float4*>(k_ws + base);
      vv = *reinterpret_cast<const float4*>(v_ws + base);
    }
    *reinterpret_cast<float4*>(&kb[jw][c4 ^ ((jw >> 4) << 2)]) = kv;
    *reinterpret_cast<float4*>(&vb[jw][c4]) = vv;
  }
  {
    float4 qv = *reinterpret_cast<const float4*>(
        q_ws + ((size_t)(b * 32 + qi) * 4 + h) * 32 + c4);
    *reinterpret_cast<float4*>(&qb[qi][c4]) = qv;
  }
  __syncthreads();

  const float scale = 0.17677669529663687f;  // 1/sqrt(32)
  float sv[16];
  float mx = -1e30f;
#pragma unroll
  for (int t = 0; t < 16; ++t) {
    int jw = (g8 << 4) + t;
    int sw = g8 << 2;             // == (jw>>4)<<2
    float acc = 0.f;
#pragma unroll
    for (int cc = 0; cc < 32; cc += 4) {
      float4 kv = *reinterpret_cast<const float4*>(&kb[jw][cc ^ sw]);
      float4 qv = *reinterpret_cast<const float4*>(&qb[qi][cc]);
      acc += qv.x * kv.x + qv.y * kv.y + qv.z * kv.z + qv.w * kv.w;
    }
    float bias = bias_ws[(((size_t)(b * 32 + qi)) * 128 + jw) * 4 + h];
    float s = fmaf(acc, scale, bias);
    sv[t] = s;
    mx = fmaxf(mx, s);
  }
#pragma unroll
  for (int m = 1; m < 8; m <<= 1) mx = fmaxf(mx, __shfl_xor(mx, m, 8));
  float sum = 0.f;
#pragma unroll
  for (int t = 0; t < 16; ++t) { float e = __expf(sv[t] - mx); sv[t] = e; sum += e; }
#pragma unroll
  for (int m = 1; m < 8; m <<= 1) sum += __shfl_xor(sum, m, 8);
  const float inv = 1.f / sum;
#pragma unroll
  for (int t = 0; t < 16; ++t) sb[(g8 << 4) + t][qi] = sv[t] * inv;
  __syncthreads();

  float4 acc = make_float4(0, 0, 0, 0);
#pragma unroll 8
  for (int jw = 0; jw < 128; ++jw) {
    float p = sb[jw][qi];
    float4 vv = *reinterpret_cast<const float4*>(&vb[jw][c4]);
    acc.x = fmaf(p, vv.x, acc.x);
    acc.y = fmaf(p, vv.y, acc.y);
    acc.z = fmaf(p, vv.z, acc.z);
    acc.w = fmaf(p, vv.w, acc.w);
  }
  {
    size_t gbase = ((size_t)(b * 32 + qi) * 4 + h) * 32 + c4;
    float4 gg = *reinterpret_cast<const float4*>(gsig_ws + gbase);
    float4 oo = make_float4(acc.x * gg.x, acc.y * gg.y, acc.z * gg.z, acc.w * gg.w);
    *reinterpret_cast<float4*>(o_ws + (size_t)(b * 32 + qi) * 128 + (h << 5) + c4) = oo;
  }
}

// ------------------------------------------------------------------
// Kernel O: out = gs * (o @ Wo), f32 store.
// ------------------------------------------------------------------
__global__ __launch_bounds__(256) void out_kernel(
    const float* __restrict__ o_ws, const float* __restrict__ gs_ws,
    const float* __restrict__ Wo, float* __restrict__ out)
{
  __shared__ float ob[8][128];
  __shared__ float wt[16384];
  const int tid = threadIdx.x;
  const int row0 = blockIdx.x * 8;
  const int mr = tid >> 5;
  const int n0 = (tid & 31) << 2;
  {
    const float4* s = reinterpret_cast<const float4*>(Wo);
    float4* d = reinterpret_cast<float4*>(wt);
#pragma unroll
    for (int i = 0; i < 16; ++i) d[tid + (i << 8)] = s[tid + (i << 8)];
    const float4* so = reinterpret_cast<const float4*>(o_ws + (size_t)row0 * 128);
    reinterpret_cast<float4*>(&ob[0][0])[tid] = so[tid];
  }
  __syncthreads();
  float acc[4] = {0, 0, 0, 0};
#pragma unroll 4
  for (int kk = 0; kk < 128; ++kk) {
    float a = ob[mr][kk];
    float4 w = *reinterpret_cast<const float4*>(&wt[kk * 128 + n0]);
    acc[0] += a * w.x;
    acc[1] += a * w.y;
    acc[2] += a * w.z;
    acc[3] += a * w.w;
  }
  float4 gg = *reinterpret_cast<const float4*>(gs_ws + (size_t)(row0 + mr) * 128 + n0);
  float4 oo = make_float4(acc[0] * gg.x, acc[1] * gg.y, acc[2] * gg.z, acc[3] * gg.w);
  *reinterpret_cast<float4*>(out + (size_t)(row0 + mr) * 128 + n0) = oo;
}

extern "C" void kernel_launch(void* const* d_in, const int* in_sizes, int n_in,
                              void* d_out, int out_size, void* d_ws, size_t ws_size,
                              hipStream_t stream) {
  const float* act     = (const float*)d_in[0];
  const float* pair    = (const float*)d_in[1];
  const float* cond    = (const float*)d_in[2];
  // d_in[3] = block_mask: analytic, ignored.
  const float* lns_q   = (const float*)d_in[4];
  const float* Wgate_q = (const float*)d_in[5];
  const float* bgate_q = (const float*)d_in[6];
  const float* Wskip_q = (const float*)d_in[7];
  const float* lns_k   = (const float*)d_in[8];
  const float* Wgate_k = (const float*)d_in[9];
  const float* bgate_k = (const float*)d_in[10];
  const float* Wskip_k = (const float*)d_in[11];
  const float* lnz_w   = (const float*)d_in[12];
  const float* Wq      = (const float*)d_in[13];
  const float* bq      = (const float*)d_in[14];
  const float* Wk      = (const float*)d_in[15];
  const float* Wv      = (const float*)d_in[16];
  const float* Wg      = (const float*)d_in[17];
  const float* Wb      = (const float*)d_in[18];
  const float* Wo      = (const float*)d_in[19];
  const float* Wgs     = (const float*)d_in[20];
  const float* bgs     = (const float*)d_in[21];

  float* ws = (float*)d_ws;
  float* q_ws    = ws;
  float* k_ws    = ws + 1 * 262144;
  float* v_ws    = ws + 2 * 262144;
  float* gsig_ws = ws + 3 * 262144;
  float* gs_ws   = ws + 4 * 262144;
  float* o_ws    = ws + 5 * 262144;
  float* bias_ws = ws + 6 * 262144;   // 2048*128*4 floats

  hipLaunchKernelGGL(proj_kernel, dim3(256), dim3(256), 0, stream,
                     act, cond, lns_q, Wgate_q, bgate_q, Wskip_q,
                     lns_k, Wgate_k, bgate_k, Wskip_k,
                     Wq, bq, Wk, Wv, Wg, Wgs, bgs,
                     q_ws, k_ws, v_ws, gsig_ws, gs_ws);
  hipLaunchKernelGGL(bias_kernel, dim3(1024), dim3(256), 0, stream,
                     pair, lnz_w, Wb, bias_ws);
  hipLaunchKernelGGL(attn_kernel, dim3(256), dim3(256), 0, stream,
                     q_ws, k_ws, v_ws, gsig_ws, bias_ws, o_ws);
  hipLaunchKernelGGL(out_kernel, dim3(256), dim3(256), 0, stream,
                     o_ws, gs_ws, Wo, (float*)d_out);
}

// Round 4
// 35.616 us; speedup vs baseline: 1.7053x; 1.7053x over previous
//
#include <hip/hip_runtime.h>
#include <hip/hip_bf16.h>

#define NTOK 2048

typedef __attribute__((ext_vector_type(8))) short short8_t;
typedef __attribute__((ext_vector_type(4))) float f32x4;

__device__ __forceinline__ float bu2f(unsigned short u) {
  unsigned int x = ((unsigned int)u) << 16; float f; __builtin_memcpy(&f, &x, 4); return f;
}
__device__ __forceinline__ unsigned short f2bu(float f) {
  __hip_bfloat16 h = __float2bfloat16(f);
  unsigned short u; __builtin_memcpy(&u, &h, 2); return u;
}
__device__ __forceinline__ float sigm(float x) { return 1.0f / (1.0f + __expf(-x)); }
__device__ __forceinline__ uint4 pack8(const float* v) {
  unsigned short u[8];
#pragma unroll
  for (int i = 0; i < 8; ++i) u[i] = f2bu(v[i]);
  uint4 r; __builtin_memcpy(&r, u, 16); return r;
}

// ------------------------------------------------------------------
// prep: (a) transpose+convert 10 weights to bf16 [n][k], folding lns into
// gate/skip weights; (b) dual LN producing xn, sn, cond as bf16.
// ------------------------------------------------------------------
__global__ __launch_bounds__(256) void prep_kernel(
    const float* __restrict__ act, const float* __restrict__ cond,
    const float* __restrict__ lns_q, const float* __restrict__ lns_k,
    const float* __restrict__ WgQ, const float* __restrict__ WsQ,
    const float* __restrict__ WgK, const float* __restrict__ WsK,
    const float* __restrict__ Wq, const float* __restrict__ Wk,
    const float* __restrict__ Wv, const float* __restrict__ Wg,
    const float* __restrict__ Wgs, const float* __restrict__ Wo,
    unsigned short* __restrict__ wt_all, unsigned short* __restrict__ xn_b,
    unsigned short* __restrict__ sn_b, unsigned short* __restrict__ cond_b)
{
  const int tid = threadIdx.x;
  const int bid = blockIdx.x;
  if (bid < 160) {
    __shared__ float tile[32][36];
    const float* srcs[10] = {WgQ, WsQ, WgK, WsK, Wq, Wk, Wv, Wg, Wgs, Wo};
    const int wi = bid >> 4, tt = bid & 15;
    const int tr = tt >> 2, tc = tt & 3;
    const float* W = srcs[wi];
    const int rr = tid >> 3, c4 = (tid & 7) << 2;
    const int k = tr * 32 + rr;
    float4 v = *(const float4*)(W + (size_t)k * 128 + tc * 32 + c4);
    float f = 1.0f;
    if (wi < 2) f = lns_q[k];
    else if (wi < 4) f = lns_k[k];
    tile[rr][c4 + 0] = v.x * f; tile[rr][c4 + 1] = v.y * f;
    tile[rr][c4 + 2] = v.z * f; tile[rr][c4 + 3] = v.w * f;
    __syncthreads();
    ushort4 o;
    o.x = f2bu(tile[c4 + 0][rr]); o.y = f2bu(tile[c4 + 1][rr]);
    o.z = f2bu(tile[c4 + 2][rr]); o.w = f2bu(tile[c4 + 3][rr]);
    *(ushort4*)(wt_all + (size_t)wi * 16384 + (size_t)(tc * 32 + rr) * 128 + tr * 32 + c4) = o;
  } else {
    const int rb = bid - 160;
    const int r = rb * 32 + (tid >> 3);
    const int c0 = (tid & 7) << 4;
    float xv[16], cv[16];
    const float4* ap = (const float4*)(act + (size_t)r * 128 + c0);
    const float4* cp = (const float4*)(cond + (size_t)r * 128 + c0);
#pragma unroll
    for (int i = 0; i < 4; ++i) {
      float4 a4 = ap[i], b4 = cp[i];
      xv[4*i+0]=a4.x; xv[4*i+1]=a4.y; xv[4*i+2]=a4.z; xv[4*i+3]=a4.w;
      cv[4*i+0]=b4.x; cv[4*i+1]=b4.y; cv[4*i+2]=b4.z; cv[4*i+3]=b4.w;
    }
    float sx=0.f, sxx=0.f, sc=0.f, scc=0.f;
#pragma unroll
    for (int i = 0; i < 16; ++i) { sx+=xv[i]; sxx+=xv[i]*xv[i]; sc+=cv[i]; scc+=cv[i]*cv[i]; }
#pragma unroll
    for (int m = 1; m < 8; m <<= 1) {
      sx += __shfl_xor(sx, m); sxx += __shfl_xor(sxx, m);
      sc += __shfl_xor(sc, m); scc += __shfl_xor(scc, m);
    }
    const float mx = sx * (1.f/128.f), vx = sxx*(1.f/128.f) - mx*mx;
    const float mc = sc * (1.f/128.f), vc = scc*(1.f/128.f) - mc*mc;
    const float rx = rsqrtf(vx + 1e-5f), rc = rsqrtf(vc + 1e-5f);
    float xo[16], so[16];
#pragma unroll
    for (int i = 0; i < 16; ++i) { xo[i] = (xv[i]-mx)*rx; so[i] = (cv[i]-mc)*rc; }
    uint4* xp = (uint4*)(xn_b + (size_t)r*128 + c0);
    xp[0] = pack8(xo); xp[1] = pack8(xo+8);
    uint4* sp = (uint4*)(sn_b + (size_t)r*128 + c0);
    sp[0] = pack8(so); sp[1] = pack8(so+8);
    uint4* cpo = (uint4*)(cond_b + (size_t)r*128 + c0);
    cpo[0] = pack8(cv); cpo[1] = pack8(cv+8);
  }
}

// ---- shared GEMM helpers (XOR-swizzled LDS, 8-elem groups) ----
__device__ __forceinline__ void stage_A32(unsigned short* a_lds, const unsigned short* src,
                                          int row0, int tid) {
  const int r = tid >> 3, c0 = (tid & 7) << 4;
  const uint4* g = (const uint4*)(src + (size_t)(row0 + r) * 128 + c0);
  uint4 v0 = g[0], v1 = g[1];
  const int x = (r & 7) << 3;
  *(uint4*)&a_lds[r * 128 + (c0 ^ x)] = v0;
  *(uint4*)&a_lds[r * 128 + ((c0 + 8) ^ x)] = v1;
}
__device__ __forceinline__ void stage_W(unsigned short* w_lds, const unsigned short* src, int tid) {
  const int n = tid >> 1;
  const int kb = (tid & 1) << 6;
  const int x = (n & 7) << 3;
  const uint4* g = (const uint4*)(src + (size_t)n * 128 + kb);
#pragma unroll
  for (int i = 0; i < 8; ++i) {
    uint4 v = g[i];
    *(uint4*)&w_lds[n * 128 + ((kb + i * 8) ^ x)] = v;
  }
}
__device__ __forceinline__ void gemm32(const unsigned short* a_lds, const unsigned short* w_lds,
                                       int lm, int kg, int wv, f32x4 acc[2][2]) {
  const int xa = (lm & 7) << 3;
#pragma unroll
  for (int ks = 0; ks < 4; ++ks) {
    const int ko = ks * 32 + kg * 8;
    short8_t av[2], bv[2];
#pragma unroll
    for (int mi = 0; mi < 2; ++mi)
      av[mi] = *(const short8_t*)&a_lds[(mi * 16 + lm) * 128 + (ko ^ xa)];
#pragma unroll
    for (int ni = 0; ni < 2; ++ni) {
      const int n = (wv * 2 + ni) * 16 + lm;
      bv[ni] = *(const short8_t*)&w_lds[n * 128 + (ko ^ xa)];
    }
#pragma unroll
    for (int mi = 0; mi < 2; ++mi)
#pragma unroll
      for (int ni = 0; ni < 2; ++ni)
        acc[mi][ni] = __builtin_amdgcn_mfma_f32_16x16x32_bf16(av[mi], bv[ni], acc[mi][ni], 0, 0, 0);
  }
}

// ------------------------------------------------------------------
// stage1: branches {a_q, a_k, gs}. gate GEMM -> stash (bf16), skip GEMM,
// combine: a = sigm(gate+bg)*xn + skip.
// ------------------------------------------------------------------
__global__ __launch_bounds__(256) void stage1_kernel(
    const unsigned short* __restrict__ wt_all, const unsigned short* __restrict__ sn_b,
    const unsigned short* __restrict__ cond_b, const unsigned short* __restrict__ xn_b,
    const float* __restrict__ bgate_q, const float* __restrict__ bgate_k,
    const float* __restrict__ bgs,
    unsigned short* __restrict__ aq_b, unsigned short* __restrict__ ak_b,
    unsigned short* __restrict__ gs_b)
{
  __shared__ unsigned short a_lds[32 * 128];
  __shared__ unsigned short w_lds[128 * 128];
  __shared__ unsigned short stash[32 * 136];
  __shared__ unsigned short xn_lds[32 * 136];
  const int tid = threadIdx.x;
  const int br = blockIdx.x / 64;
  const int rt = blockIdx.x % 64;
  const int row0 = rt * 32;
  const int l = tid & 63, wv = tid >> 6;
  const int lm = l & 15, kg = l >> 4;

  stage_A32(a_lds, (br == 2) ? cond_b : sn_b, row0, tid);
  if (br < 2) {
    const int r = tid >> 3, c0 = (tid & 7) << 4;
    const uint4* g = (const uint4*)(xn_b + (size_t)(row0 + r) * 128 + c0);
    uint4 v0 = g[0], v1 = g[1];
    *(uint4*)&xn_lds[r * 136 + c0] = v0;
    *(uint4*)&xn_lds[r * 136 + c0 + 8] = v1;
  }
  const int w0 = (br == 0) ? 0 : (br == 1) ? 2 : 8;
  stage_W(w_lds, wt_all + (size_t)w0 * 16384, tid);
  __syncthreads();

  f32x4 acc[2][2] = {};
  gemm32(a_lds, w_lds, lm, kg, wv, acc);

  if (br == 2) {
    float bgv[2];
#pragma unroll
    for (int ni = 0; ni < 2; ++ni) bgv[ni] = bgs[(wv * 2 + ni) * 16 + lm];
#pragma unroll
    for (int mi = 0; mi < 2; ++mi)
#pragma unroll
      for (int ni = 0; ni < 2; ++ni)
#pragma unroll
        for (int r = 0; r < 4; ++r) {
          const int rl = mi * 16 + kg * 4 + r;
          const int n = (wv * 2 + ni) * 16 + lm;
          gs_b[(size_t)(row0 + rl) * 128 + n] = f2bu(sigm(acc[mi][ni][r] + bgv[ni]));
        }
    return;
  }
#pragma unroll
  for (int mi = 0; mi < 2; ++mi)
#pragma unroll
    for (int ni = 0; ni < 2; ++ni)
#pragma unroll
      for (int r = 0; r < 4; ++r) {
        const int rl = mi * 16 + kg * 4 + r;
        const int n = (wv * 2 + ni) * 16 + lm;
        stash[rl * 136 + n] = f2bu(acc[mi][ni][r]);
      }
  __syncthreads();
  stage_W(w_lds, wt_all + (size_t)(w0 + 1) * 16384, tid);
  __syncthreads();
  f32x4 acc2[2][2] = {};
  gemm32(a_lds, w_lds, lm, kg, wv, acc2);
  const float* bg = (br == 0) ? bgate_q : bgate_k;
  unsigned short* dst = (br == 0) ? aq_b : ak_b;
  float bgv[2];
#pragma unroll
  for (int ni = 0; ni < 2; ++ni) bgv[ni] = bg[(wv * 2 + ni) * 16 + lm];
#pragma unroll
  for (int mi = 0; mi < 2; ++mi)
#pragma unroll
    for (int ni = 0; ni < 2; ++ni)
#pragma unroll
      for (int r = 0; r < 4; ++r) {
        const int rl = mi * 16 + kg * 4 + r;
        const int n = (wv * 2 + ni) * 16 + lm;
        const float gate = sigm(bu2f(stash[rl * 136 + n]) + bgv[ni]);
        const float a = gate * bu2f(xn_lds[rl * 136 + n]) + acc2[mi][ni][r];
        dst[(size_t)(row0 + rl) * 128 + n] = f2bu(a);
      }
}

// ------------------------------------------------------------------
// stage2: branches {q(+bq, *scale), g(sigmoid), k, v}
// ------------------------------------------------------------------
__global__ __launch_bounds__(256) void stage2_kernel(
    const unsigned short* __restrict__ wt_all, const unsigned short* __restrict__ aq_b,
    const unsigned short* __restrict__ ak_b, const float* __restrict__ bq,
    unsigned short* __restrict__ q_b, unsigned short* __restrict__ k_b,
    unsigned short* __restrict__ v_b, unsigned short* __restrict__ gsig_b)
{
  __shared__ unsigned short a_lds[32 * 128];
  __shared__ unsigned short w_lds[128 * 128];
  const int tid = threadIdx.x;
  const int br = blockIdx.x >> 6;
  const int rt = blockIdx.x & 63;
  const int row0 = rt * 32;
  const int l = tid & 63, wv = tid >> 6;
  const int lm = l & 15, kg = l >> 4;
  const int wsel = (br == 0) ? 4 : (br == 1) ? 7 : (br == 2) ? 5 : 6;
  stage_A32(a_lds, (br < 2) ? aq_b : ak_b, row0, tid);
  stage_W(w_lds, wt_all + (size_t)wsel * 16384, tid);
  __syncthreads();
  f32x4 acc[2][2] = {};
  gemm32(a_lds, w_lds, lm, kg, wv, acc);
  unsigned short* dst = (br == 0) ? q_b : (br == 1) ? gsig_b : (br == 2) ? k_b : v_b;
  float bqv[2] = {0.f, 0.f};
  if (br == 0) {
#pragma unroll
    for (int ni = 0; ni < 2; ++ni) bqv[ni] = bq[(wv * 2 + ni) * 16 + lm];
  }
  const float scale = 0.17677669529663687f;
#pragma unroll
  for (int mi = 0; mi < 2; ++mi)
#pragma unroll
    for (int ni = 0; ni < 2; ++ni)
#pragma unroll
      for (int r = 0; r < 4; ++r) {
        const int rl = mi * 16 + kg * 4 + r;
        const int n = (wv * 2 + ni) * 16 + lm;
        float v = acc[mi][ni][r];
        if (br == 0) v = (v + bqv[ni]) * scale;
        else if (br == 1) v = sigm(v);
        dst[(size_t)(row0 + rl) * 128 + n] = f2bu(v);
      }
}

// ------------------------------------------------------------------
// bias: windowed pair LN -> @Wb, h-major bf16 out; OOB -> -1e9 (mask)
// ------------------------------------------------------------------
__global__ __launch_bounds__(256) void bias_kernel(
    const float* __restrict__ pair, const float* __restrict__ lnz_w,
    const float* __restrict__ Wb, unsigned short* __restrict__ bias_h)
{
  __shared__ float lw[16], wb[16][4];
  const int tid = threadIdx.x;
  if (tid < 16) lw[tid] = lnz_w[tid];
  if (tid < 64) wb[tid >> 2][tid & 3] = Wb[tid];
  __syncthreads();
  const int idx = blockIdx.x * 256 + tid;
  const int i = idx >> 7, jw = idx & 127;
  const int j = ((i >> 5) << 5) - 48 + jw;
  float bo[4] = {-1e9f, -1e9f, -1e9f, -1e9f};
  if (j >= 0 && j < NTOK) {
    const float4* p = (const float4*)(pair + ((size_t)i * NTOK + j) * 16);
    float4 z0 = p[0], z1 = p[1], z2 = p[2], z3 = p[3];
    float z[16] = {z0.x, z0.y, z0.z, z0.w, z1.x, z1.y, z1.z, z1.w,
                   z2.x, z2.y, z2.z, z2.w, z3.x, z3.y, z3.z, z3.w};
    float s = 0.f, ss = 0.f;
#pragma unroll
    for (int c = 0; c < 16; ++c) { s += z[c]; ss += z[c]*z[c]; }
    const float m = s * (1.f/16.f), v = ss * (1.f/16.f) - m*m;
    const float r = rsqrtf(v + 1e-5f);
    bo[0] = bo[1] = bo[2] = bo[3] = 0.f;
#pragma unroll
    for (int c = 0; c < 16; ++c) {
      const float zn = (z[c] - m) * r * lw[c];
      bo[0] += zn * wb[c][0]; bo[1] += zn * wb[c][1];
      bo[2] += zn * wb[c][2]; bo[3] += zn * wb[c][3];
    }
  }
#pragma unroll
  for (int h = 0; h < 4; ++h)
    bias_h[(size_t)h * (NTOK * 128) + idx] = f2bu(bo[h]);
}

// ------------------------------------------------------------------
// attn: per (qblock, head); MFMA QK^T + f32 softmax + MFMA PV
// ------------------------------------------------------------------
__global__ __launch_bounds__(256) void attn_kernel(
    const unsigned short* __restrict__ q_b, const unsigned short* __restrict__ k_b,
    const unsigned short* __restrict__ v_b, const unsigned short* __restrict__ gsig_b,
    const unsigned short* __restrict__ bias_h, unsigned short* __restrict__ o_b)
{
  __shared__ unsigned short k_lds[128 * 64];
  __shared__ unsigned short vt[32 * 128];
  __shared__ unsigned short p_lds[32 * 128];
  __shared__ unsigned short q_lds[32 * 64];
  __shared__ unsigned short bias_lds[32 * 136];
  __shared__ float mxlds[4][32];
  __shared__ float smlds[4][32];
  __shared__ f32x4 op[16][64];
  const int tid = threadIdx.x;
  const int h = blockIdx.x & 3, b = blockIdx.x >> 2;
  const int j0 = b * 32 - 48;
  const int l = tid & 63, wv = tid >> 6;
  const int lm = l & 15, kg = l >> 4;

  { // Q stage
    const int r = tid >> 3, c0 = (tid & 7) << 2;
    ushort4 v = *(const ushort4*)(q_b + (size_t)(b * 32 + r) * 128 + h * 32 + c0);
    *(ushort4*)&q_lds[r * 64 + (c0 ^ ((r & 7) << 3))] = v;
  }
  { // bias stage
    const int r = tid >> 3, c0 = (tid & 7) << 4;
    const uint4* g = (const uint4*)(bias_h + (size_t)h * (NTOK * 128) + (size_t)(b * 32 + r) * 128 + c0);
    uint4 v0 = g[0], v1 = g[1];
    *(uint4*)&bias_lds[r * 136 + c0] = v0;
    *(uint4*)&bias_lds[r * 136 + c0 + 8] = v1;
  }
  { // K + V stage (V transposed)
    const int jw = tid >> 1, cb = (tid & 1) << 4;
    const int j = j0 + jw;
    uint4 kv0 = {0,0,0,0}, kv1 = {0,0,0,0}, vv0 = {0,0,0,0}, vv1 = {0,0,0,0};
    if (j >= 0 && j < NTOK) {
      const uint4* gk = (const uint4*)(k_b + (size_t)j * 128 + h * 32 + cb);
      kv0 = gk[0]; kv1 = gk[1];
      const uint4* gv = (const uint4*)(v_b + (size_t)j * 128 + h * 32 + cb);
      vv0 = gv[0]; vv1 = gv[1];
    }
    const int xk = (jw & 7) << 3;
    *(uint4*)&k_lds[jw * 64 + (cb ^ xk)] = kv0;
    *(uint4*)&k_lds[jw * 64 + ((cb + 8) ^ xk)] = kv1;
    unsigned short tmp[16];
    __builtin_memcpy(tmp, &vv0, 16);
    __builtin_memcpy(tmp + 8, &vv1, 16);
#pragma unroll
    for (int i2 = 0; i2 < 16; ++i2) {
      const int c = cb + i2;
      vt[c * 128 + ((jw & 7) | ((jw & 120) ^ ((c & 7) << 3)))] = tmp[i2];
    }
  }
  __syncthreads();

  // QK^T (C=32 -> single MFMA K-step)
  f32x4 sc[2][2] = {};
  {
    const int xa = (lm & 7) << 3;
    short8_t aq[2], bk[2];
#pragma unroll
    for (int mi = 0; mi < 2; ++mi)
      aq[mi] = *(const short8_t*)&q_lds[(mi * 16 + lm) * 64 + ((kg * 8) ^ xa)];
#pragma unroll
    for (int ni = 0; ni < 2; ++ni) {
      const int key = (wv * 2 + ni) * 16 + lm;
      bk[ni] = *(const short8_t*)&k_lds[key * 64 + ((kg * 8) ^ ((key & 7) << 3))];
    }
#pragma unroll
    for (int mi = 0; mi < 2; ++mi)
#pragma unroll
      for (int ni = 0; ni < 2; ++ni)
        sc[mi][ni] = __builtin_amdgcn_mfma_f32_16x16x32_bf16(aq[mi], bk[ni], sc[mi][ni], 0, 0, 0);
  }
  float sv[2][2][4];
#pragma unroll
  for (int mi = 0; mi < 2; ++mi)
#pragma unroll
    for (int ni = 0; ni < 2; ++ni)
#pragma unroll
      for (int r = 0; r < 4; ++r) {
        const int q = mi * 16 + kg * 4 + r;
        const int key = (wv * 2 + ni) * 16 + lm;
        sv[mi][ni][r] = sc[mi][ni][r] + bu2f(bias_lds[q * 136 + key]);
      }
#pragma unroll
  for (int mi = 0; mi < 2; ++mi)
#pragma unroll
    for (int r = 0; r < 4; ++r) {
      float m0 = fmaxf(sv[mi][0][r], sv[mi][1][r]);
#pragma unroll
      for (int msk = 1; msk < 16; msk <<= 1) m0 = fmaxf(m0, __shfl_xor(m0, msk));
      if (lm == 0) mxlds[wv][mi * 16 + kg * 4 + r] = m0;
    }
  __syncthreads();
#pragma unroll
  for (int mi = 0; mi < 2; ++mi)
#pragma unroll
    for (int r = 0; r < 4; ++r) {
      const int q = mi * 16 + kg * 4 + r;
      const float m = fmaxf(fmaxf(mxlds[0][q], mxlds[1][q]), fmaxf(mxlds[2][q], mxlds[3][q]));
      float s = 0.f;
#pragma unroll
      for (int ni = 0; ni < 2; ++ni) {
        const float e = __expf(sv[mi][ni][r] - m);
        const int key = (wv * 2 + ni) * 16 + lm;
        p_lds[q * 128 + ((key & 7) | ((key & 120) ^ ((q & 7) << 3)))] = f2bu(e);
        s += e;
      }
#pragma unroll
      for (int msk = 1; msk < 16; msk <<= 1) s += __shfl_xor(s, msk);
      if (lm == 0) smlds[wv][q] = s;
    }
  // PV: each wave handles its own 32 keys (wave-local P)
  f32x4 oacc[2][2] = {};
  {
    const int key0 = wv * 32 + kg * 8;
    short8_t pa[2], vbf[2];
#pragma unroll
    for (int mi = 0; mi < 2; ++mi) {
      const int q = mi * 16 + lm;
      pa[mi] = *(const short8_t*)&p_lds[q * 128 + (key0 ^ ((q & 7) << 3))];
    }
#pragma unroll
    for (int ct = 0; ct < 2; ++ct) {
      const int c = ct * 16 + lm;
      vbf[ct] = *(const short8_t*)&vt[c * 128 + (key0 ^ ((c & 7) << 3))];
    }
#pragma unroll
    for (int mi = 0; mi < 2; ++mi)
#pragma unroll
      for (int ct = 0; ct < 2; ++ct)
        oacc[mi][ct] = __builtin_amdgcn_mfma_f32_16x16x32_bf16(pa[mi], vbf[ct], oacc[mi][ct], 0, 0, 0);
  }
#pragma unroll
  for (int mi = 0; mi < 2; ++mi)
#pragma unroll
    for (int ct = 0; ct < 2; ++ct)
      op[wv * 4 + mi * 2 + ct][l] = oacc[mi][ct];
  __syncthreads();
  { // reduce partials + gate + store
    const int q = tid >> 3, c0 = (tid & 7) << 2;
    const int mt = q >> 4, g = (q >> 2) & 3, r = q & 3;
    const float tot = smlds[0][q] + smlds[1][q] + smlds[2][q] + smlds[3][q];
    const float inv = 1.f / tot;
    ushort4 gg = *(const ushort4*)(gsig_b + (size_t)(b * 32 + q) * 128 + h * 32 + c0);
    unsigned short gga[4] = {gg.x, gg.y, gg.z, gg.w};
    unsigned short outa[4];
#pragma unroll
    for (int i2 = 0; i2 < 4; ++i2) {
      const int c = c0 + i2;
      const int ct = c >> 4, lane = g * 16 + (c & 15);
      float s = 0.f;
#pragma unroll
      for (int w2 = 0; w2 < 4; ++w2)
        s += ((const float*)&op[w2 * 4 + mt * 2 + ct][lane])[r];
      outa[i2] = f2bu(s * inv * bu2f(gga[i2]));
    }
    ushort4 ov; ov.x = outa[0]; ov.y = outa[1]; ov.z = outa[2]; ov.w = outa[3];
    *(ushort4*)(o_b + (size_t)(b * 32 + q) * 128 + h * 32 + c0) = ov;
  }
}

// ------------------------------------------------------------------
// out: out = gs * (o @ Wo), f32 store
// ------------------------------------------------------------------
__global__ __launch_bounds__(256) void out_kernel(
    const unsigned short* __restrict__ wt_all, const unsigned short* __restrict__ o_b,
    const unsigned short* __restrict__ gs_b, float* __restrict__ out)
{
  __shared__ unsigned short a_lds[16 * 128];
  __shared__ unsigned short w_lds[128 * 128];
  const int tid = threadIdx.x;
  const int row0 = blockIdx.x * 16;
  const int l = tid & 63, wv = tid >> 6;
  const int lm = l & 15, kg = l >> 4;
  {
    const int r = tid >> 4, c0 = (tid & 15) << 3;
    uint4 v = *(const uint4*)(o_b + (size_t)(row0 + r) * 128 + c0);
    *(uint4*)&a_lds[r * 128 + (c0 ^ ((r & 7) << 3))] = v;
  }
  stage_W(w_lds, wt_all + (size_t)9 * 16384, tid);
  __syncthreads();
  f32x4 acc[2] = {};
  const int xa = (lm & 7) << 3;
#pragma unroll
  for (int ks = 0; ks < 4; ++ks) {
    const int ko = ks * 32 + kg * 8;
    short8_t av = *(const short8_t*)&a_lds[lm * 128 + (ko ^ xa)];
#pragma unroll
    for (int ni = 0; ni < 2; ++ni) {
      const int n = (wv * 2 + ni) * 16 + lm;
      short8_t bv = *(const short8_t*)&w_lds[n * 128 + (ko ^ xa)];
      acc[ni] = __builtin_amdgcn_mfma_f32_16x16x32_bf16(av, bv, acc[ni], 0, 0, 0);
    }
  }
#pragma unroll
  for (int ni = 0; ni < 2; ++ni)
#pragma unroll
    for (int r = 0; r < 4; ++r) {
      const int rl = kg * 4 + r;
      const int n = (wv * 2 + ni) * 16 + lm;
      const float gsv = bu2f(gs_b[(size_t)(row0 + rl) * 128 + n]);
      out[(size_t)(row0 + rl) * 128 + n] = acc[ni][r] * gsv;
    }
}

extern "C" void kernel_launch(void* const* d_in, const int* in_sizes, int n_in,
                              void* d_out, int out_size, void* d_ws, size_t ws_size,
                              hipStream_t stream) {
  const float* act     = (const float*)d_in[0];
  const float* pair    = (const float*)d_in[1];
  const float* cond    = (const float*)d_in[2];
  const float* lns_q   = (const float*)d_in[4];
  const float* Wgate_q = (const float*)d_in[5];
  const float* bgate_q = (const float*)d_in[6];
  const float* Wskip_q = (const float*)d_in[7];
  const float* lns_k   = (const float*)d_in[8];
  const float* Wgate_k = (const float*)d_in[9];
  const float* bgate_k = (const float*)d_in[10];
  const float* Wskip_k = (const float*)d_in[11];
  const float* lnz_w   = (const float*)d_in[12];
  const float* Wq      = (const float*)d_in[13];
  const float* bq      = (const float*)d_in[14];
  const float* Wk      = (const float*)d_in[15];
  const float* Wv      = (const float*)d_in[16];
  const float* Wg      = (const float*)d_in[17];
  const float* Wb      = (const float*)d_in[18];
  const float* Wo      = (const float*)d_in[19];
  const float* Wgs     = (const float*)d_in[20];
  const float* bgs     = (const float*)d_in[21];
  float* out           = (float*)d_out;

  unsigned short* ws = (unsigned short*)d_ws;
  unsigned short* wt_all = ws;                      // 10*16384
  unsigned short* xn_b   = ws + 163840;
  unsigned short* sn_b   = ws + 425984;
  unsigned short* cond_b = ws + 688128;
  unsigned short* aq_b   = ws + 950272;
  unsigned short* ak_b   = ws + 1212416;
  unsigned short* q_b    = ws + 1474560;
  unsigned short* k_b    = ws + 1736704;
  unsigned short* v_b    = ws + 1998848;
  unsigned short* gsig_b = ws + 2260992;
  unsigned short* gs_b   = ws + 2523136;
  unsigned short* o_b    = ws + 2785280;
  unsigned short* bias_h = ws + 3047424;            // 4*2048*128

  hipLaunchKernelGGL(prep_kernel, dim3(224), dim3(256), 0, stream,
                     act, cond, lns_q, lns_k,
                     Wgate_q, Wskip_q, Wgate_k, Wskip_k,
                     Wq, Wk, Wv, Wg, Wgs, Wo,
                     wt_all, xn_b, sn_b, cond_b);
  hipLaunchKernelGGL(bias_kernel, dim3(1024), dim3(256), 0, stream,
                     pair, lnz_w, Wb, bias_h);
  hipLaunchKernelGGL(stage1_kernel, dim3(192), dim3(256), 0, stream,
                     wt_all, sn_b, cond_b, xn_b, bgate_q, bgate_k, bgs,
                     aq_b, ak_b, gs_b);
  hipLaunchKernelGGL(stage2_kernel, dim3(256), dim3(256), 0, stream,
                     wt_all, aq_b, ak_b, bq, q_b, k_b, v_b, gsig_b);
  hipLaunchKernelGGL(attn_kernel, dim3(256), dim3(256), 0, stream,
                     q_b, k_b, v_b, gsig_b, bias_h, o_b);
  hipLaunchKernelGGL(out_kernel, dim3(128), dim3(256), 0, stream,
                     wt_all, o_b, gs_b, out);
}

// Round 5
// 34.409 us; speedup vs baseline: 1.7651x; 1.0351x over previous
//
#include <hip/hip_runtime.h>
#include <hip/hip_bf16.h>

#define NTOK 2048

typedef __attribute__((ext_vector_type(8))) short short8_t;
typedef __attribute__((ext_vector_type(4))) float f32x4;

__device__ __forceinline__ float bu2f(unsigned short u) {
  unsigned int x = ((unsigned int)u) << 16; float f; __builtin_memcpy(&f, &x, 4); return f;
}
__device__ __forceinline__ unsigned short f2bu(float f) {
  __hip_bfloat16 h = __float2bfloat16(f);
  unsigned short u; __builtin_memcpy(&u, &h, 2); return u;
}
__device__ __forceinline__ float sigm(float x) { return 1.0f / (1.0f + __expf(-x)); }
__device__ __forceinline__ uint4 pack8(const float* v) {
  unsigned short u[8];
#pragma unroll
  for (int i = 0; i < 8; ++i) u[i] = f2bu(v[i]);
  uint4 r; __builtin_memcpy(&r, u, 16); return r;
}

// ------------------------------------------------------------------
// K1: fused prep (weights transpose+fold, dual LN) + windowed pair bias.
//   blocks [0,1024): bias; [1024,1184): weights; [1184,1248): LN
// ------------------------------------------------------------------
__global__ __launch_bounds__(256) void prep_bias_kernel(
    const float* __restrict__ act, const float* __restrict__ cond,
    const float* __restrict__ lns_q, const float* __restrict__ lns_k,
    const float* __restrict__ WgQ, const float* __restrict__ WsQ,
    const float* __restrict__ WgK, const float* __restrict__ WsK,
    const float* __restrict__ Wq, const float* __restrict__ Wk,
    const float* __restrict__ Wv, const float* __restrict__ Wg,
    const float* __restrict__ Wgs, const float* __restrict__ Wo,
    const float* __restrict__ pair, const float* __restrict__ lnz_w,
    const float* __restrict__ Wb,
    unsigned short* __restrict__ wt_all, unsigned short* __restrict__ xn_b,
    unsigned short* __restrict__ sn_b, unsigned short* __restrict__ cond_b,
    unsigned short* __restrict__ bias_h)
{
  const int tid = threadIdx.x;
  const int bid = blockIdx.x;
  __shared__ float tile[32][36];
  __shared__ float lw[16], wb[16][4];

  if (bid < 1024) {
    // ---- windowed pair bias ----
    if (tid < 16) lw[tid] = lnz_w[tid];
    if (tid < 64) wb[tid >> 2][tid & 3] = Wb[tid];
    __syncthreads();
    const int idx = bid * 256 + tid;
    const int i = idx >> 7, jw = idx & 127;
    const int j = ((i >> 5) << 5) - 48 + jw;
    float bo[4] = {-1e9f, -1e9f, -1e9f, -1e9f};
    if (j >= 0 && j < NTOK) {
      const float4* p = (const float4*)(pair + ((size_t)i * NTOK + j) * 16);
      float4 z0 = p[0], z1 = p[1], z2 = p[2], z3 = p[3];
      float z[16] = {z0.x, z0.y, z0.z, z0.w, z1.x, z1.y, z1.z, z1.w,
                     z2.x, z2.y, z2.z, z2.w, z3.x, z3.y, z3.z, z3.w};
      float s = 0.f, ss = 0.f;
#pragma unroll
      for (int c = 0; c < 16; ++c) { s += z[c]; ss += z[c]*z[c]; }
      const float m = s * (1.f/16.f), v = ss * (1.f/16.f) - m*m;
      const float r = rsqrtf(v + 1e-5f);
      bo[0] = bo[1] = bo[2] = bo[3] = 0.f;
#pragma unroll
      for (int c = 0; c < 16; ++c) {
        const float zn = (z[c] - m) * r * lw[c];
        bo[0] += zn * wb[c][0]; bo[1] += zn * wb[c][1];
        bo[2] += zn * wb[c][2]; bo[3] += zn * wb[c][3];
      }
    }
#pragma unroll
    for (int h = 0; h < 4; ++h)
      bias_h[(size_t)h * (NTOK * 128) + idx] = f2bu(bo[h]);
  } else if (bid < 1184) {
    // ---- weight transpose + fold ----
    const float* srcs[10] = {WgQ, WsQ, WgK, WsK, Wq, Wk, Wv, Wg, Wgs, Wo};
    const int wbk = bid - 1024;
    const int wi = wbk >> 4, tt = wbk & 15;
    const int tr = tt >> 2, tc = tt & 3;
    const float* W = srcs[wi];
    const int rr = tid >> 3, c4 = (tid & 7) << 2;
    const int k = tr * 32 + rr;
    float4 v = *(const float4*)(W + (size_t)k * 128 + tc * 32 + c4);
    float f = 1.0f;
    if (wi < 2) f = lns_q[k];
    else if (wi < 4) f = lns_k[k];
    tile[rr][c4 + 0] = v.x * f; tile[rr][c4 + 1] = v.y * f;
    tile[rr][c4 + 2] = v.z * f; tile[rr][c4 + 3] = v.w * f;
    __syncthreads();
    ushort4 o;
    o.x = f2bu(tile[c4 + 0][rr]); o.y = f2bu(tile[c4 + 1][rr]);
    o.z = f2bu(tile[c4 + 2][rr]); o.w = f2bu(tile[c4 + 3][rr]);
    *(ushort4*)(wt_all + (size_t)wi * 16384 + (size_t)(tc * 32 + rr) * 128 + tr * 32 + c4) = o;
  } else {
    // ---- dual LN ----
    const int rb = bid - 1184;
    const int r = rb * 32 + (tid >> 3);
    const int c0 = (tid & 7) << 4;
    float xv[16], cv[16];
    const float4* ap = (const float4*)(act + (size_t)r * 128 + c0);
    const float4* cp = (const float4*)(cond + (size_t)r * 128 + c0);
#pragma unroll
    for (int i = 0; i < 4; ++i) {
      float4 a4 = ap[i], b4 = cp[i];
      xv[4*i+0]=a4.x; xv[4*i+1]=a4.y; xv[4*i+2]=a4.z; xv[4*i+3]=a4.w;
      cv[4*i+0]=b4.x; cv[4*i+1]=b4.y; cv[4*i+2]=b4.z; cv[4*i+3]=b4.w;
    }
    float sx=0.f, sxx=0.f, sc=0.f, scc=0.f;
#pragma unroll
    for (int i = 0; i < 16; ++i) { sx+=xv[i]; sxx+=xv[i]*xv[i]; sc+=cv[i]; scc+=cv[i]*cv[i]; }
#pragma unroll
    for (int m = 1; m < 8; m <<= 1) {
      sx += __shfl_xor(sx, m); sxx += __shfl_xor(sxx, m);
      sc += __shfl_xor(sc, m); scc += __shfl_xor(scc, m);
    }
    const float mx = sx * (1.f/128.f), vx = sxx*(1.f/128.f) - mx*mx;
    const float mc = sc * (1.f/128.f), vc = scc*(1.f/128.f) - mc*mc;
    const float rx = rsqrtf(vx + 1e-5f), rc = rsqrtf(vc + 1e-5f);
    float xo[16], so[16];
#pragma unroll
    for (int i = 0; i < 16; ++i) { xo[i] = (xv[i]-mx)*rx; so[i] = (cv[i]-mc)*rc; }
    uint4* xp = (uint4*)(xn_b + (size_t)r*128 + c0);
    xp[0] = pack8(xo); xp[1] = pack8(xo+8);
    uint4* sp = (uint4*)(sn_b + (size_t)r*128 + c0);
    sp[0] = pack8(so); sp[1] = pack8(so+8);
    uint4* cpo = (uint4*)(cond_b + (size_t)r*128 + c0);
    cpo[0] = pack8(cv); cpo[1] = pack8(cv+8);
  }
}

// ---- shared GEMM helpers (XOR-swizzled LDS, 8-elem groups) ----
__device__ __forceinline__ void stage_A32(unsigned short* a_lds, const unsigned short* src,
                                          int row0, int tid) {
  const int r = tid >> 3, c0 = (tid & 7) << 4;
  const uint4* g = (const uint4*)(src + (size_t)(row0 + r) * 128 + c0);
  uint4 v0 = g[0], v1 = g[1];
  const int x = (r & 7) << 3;
  *(uint4*)&a_lds[r * 128 + (c0 ^ x)] = v0;
  *(uint4*)&a_lds[r * 128 + ((c0 + 8) ^ x)] = v1;
}
__device__ __forceinline__ void stage_W(unsigned short* w_lds, const unsigned short* src, int tid) {
  const int n = tid >> 1;
  const int kb = (tid & 1) << 6;
  const int x = (n & 7) << 3;
  const uint4* g = (const uint4*)(src + (size_t)n * 128 + kb);
#pragma unroll
  for (int i = 0; i < 8; ++i) {
    uint4 v = g[i];
    *(uint4*)&w_lds[n * 128 + ((kb + i * 8) ^ x)] = v;
  }
}
__device__ __forceinline__ void gemm32(const unsigned short* a_lds, const unsigned short* w_lds,
                                       int lm, int kg, int wv, f32x4 acc[2][2]) {
  const int xa = (lm & 7) << 3;
#pragma unroll
  for (int ks = 0; ks < 4; ++ks) {
    const int ko = ks * 32 + kg * 8;
    short8_t av[2], bv[2];
#pragma unroll
    for (int mi = 0; mi < 2; ++mi)
      av[mi] = *(const short8_t*)&a_lds[(mi * 16 + lm) * 128 + (ko ^ xa)];
#pragma unroll
    for (int ni = 0; ni < 2; ++ni) {
      const int n = (wv * 2 + ni) * 16 + lm;
      bv[ni] = *(const short8_t*)&w_lds[n * 128 + (ko ^ xa)];
    }
#pragma unroll
    for (int mi = 0; mi < 2; ++mi)
#pragma unroll
      for (int ni = 0; ni < 2; ++ni)
        acc[mi][ni] = __builtin_amdgcn_mfma_f32_16x16x32_bf16(av[mi], bv[ni], acc[mi][ni], 0, 0, 0);
  }
}

// ------------------------------------------------------------------
// K2: fused projections. 192 blocks = 64 row-tiles x {q+g, k+v, gs}.
//   br0: a_q = sigm(sn@WgQ+bg)*xn + sn@WsQ; q = (a_q@Wq+bq)*scale; gsig = sigm(a_q@Wg)
//   br1: a_k likewise; k = a_k@Wk; v = a_k@Wv
//   br2: gs = sigm(cond@Wgs + bgs)
// ------------------------------------------------------------------
__global__ __launch_bounds__(256) void proj_kernel(
    const unsigned short* __restrict__ wt_all, const unsigned short* __restrict__ xn_b,
    const unsigned short* __restrict__ sn_b, const unsigned short* __restrict__ cond_b,
    const float* __restrict__ bgate_q, const float* __restrict__ bgate_k,
    const float* __restrict__ bq, const float* __restrict__ bgs,
    unsigned short* __restrict__ q_b, unsigned short* __restrict__ k_b,
    unsigned short* __restrict__ v_b, unsigned short* __restrict__ gsig_b,
    unsigned short* __restrict__ gs_b)
{
  __shared__ unsigned short a_lds[32 * 128];
  __shared__ unsigned short a2_lds[32 * 128];
  __shared__ unsigned short w_lds[128 * 128];
  __shared__ unsigned short stash[32 * 136];
  __shared__ unsigned short xn_lds[32 * 136];
  const int tid = threadIdx.x;
  const int br = blockIdx.x / 64;
  const int rt = blockIdx.x % 64;
  const int row0 = rt * 32;
  const int l = tid & 63, wv = tid >> 6;
  const int lm = l & 15, kg = l >> 4;

  if (br == 2) {
    stage_A32(a_lds, cond_b, row0, tid);
    stage_W(w_lds, wt_all + (size_t)8 * 16384, tid);
    __syncthreads();
    f32x4 acc[2][2] = {};
    gemm32(a_lds, w_lds, lm, kg, wv, acc);
    float bgv[2];
#pragma unroll
    for (int ni = 0; ni < 2; ++ni) bgv[ni] = bgs[(wv * 2 + ni) * 16 + lm];
#pragma unroll
    for (int mi = 0; mi < 2; ++mi)
#pragma unroll
      for (int ni = 0; ni < 2; ++ni)
#pragma unroll
        for (int r = 0; r < 4; ++r) {
          const int rl = mi * 16 + kg * 4 + r;
          const int n = (wv * 2 + ni) * 16 + lm;
          gs_b[(size_t)(row0 + rl) * 128 + n] = f2bu(sigm(acc[mi][ni][r] + bgv[ni]));
        }
    return;
  }

  const int w0 = (br == 0) ? 0 : 2;
  stage_A32(a_lds, sn_b, row0, tid);
  {
    const int r = tid >> 3, c0 = (tid & 7) << 4;
    const uint4* g = (const uint4*)(xn_b + (size_t)(row0 + r) * 128 + c0);
    uint4 v0 = g[0], v1 = g[1];
    *(uint4*)&xn_lds[r * 136 + c0] = v0;
    *(uint4*)&xn_lds[r * 136 + c0 + 8] = v1;
  }
  stage_W(w_lds, wt_all + (size_t)w0 * 16384, tid);
  __syncthreads();
  f32x4 acc[2][2] = {};
  gemm32(a_lds, w_lds, lm, kg, wv, acc);
#pragma unroll
  for (int mi = 0; mi < 2; ++mi)
#pragma unroll
    for (int ni = 0; ni < 2; ++ni)
#pragma unroll
      for (int r = 0; r < 4; ++r) {
        const int rl = mi * 16 + kg * 4 + r;
        const int n = (wv * 2 + ni) * 16 + lm;
        stash[rl * 136 + n] = f2bu(acc[mi][ni][r]);
      }
  __syncthreads();
  stage_W(w_lds, wt_all + (size_t)(w0 + 1) * 16384, tid);
  __syncthreads();
  f32x4 acc2[2][2] = {};
  gemm32(a_lds, w_lds, lm, kg, wv, acc2);
  {
    const float* bg = (br == 0) ? bgate_q : bgate_k;
    float bgv[2];
#pragma unroll
    for (int ni = 0; ni < 2; ++ni) bgv[ni] = bg[(wv * 2 + ni) * 16 + lm];
#pragma unroll
    for (int mi = 0; mi < 2; ++mi)
#pragma unroll
      for (int ni = 0; ni < 2; ++ni)
#pragma unroll
        for (int r = 0; r < 4; ++r) {
          const int rl = mi * 16 + kg * 4 + r;
          const int n = (wv * 2 + ni) * 16 + lm;
          const float gate = sigm(bu2f(stash[rl * 136 + n]) + bgv[ni]);
          const float a = gate * bu2f(xn_lds[rl * 136 + n]) + acc2[mi][ni][r];
          a2_lds[rl * 128 + (n ^ ((rl & 7) << 3))] = f2bu(a);
        }
  }
  __syncthreads();
  // third GEMM: q (br0) / k (br1)
  stage_W(w_lds, wt_all + (size_t)((br == 0) ? 4 : 5) * 16384, tid);
  __syncthreads();
  f32x4 acc3[2][2] = {};
  gemm32(a2_lds, w_lds, lm, kg, wv, acc3);
  {
    const float scale = 0.17677669529663687f;
    float bqv[2] = {0.f, 0.f};
    if (br == 0) {
#pragma unroll
      for (int ni = 0; ni < 2; ++ni) bqv[ni] = bq[(wv * 2 + ni) * 16 + lm];
    }
    unsigned short* dst = (br == 0) ? q_b : k_b;
#pragma unroll
    for (int mi = 0; mi < 2; ++mi)
#pragma unroll
      for (int ni = 0; ni < 2; ++ni)
#pragma unroll
        for (int r = 0; r < 4; ++r) {
          const int rl = mi * 16 + kg * 4 + r;
          const int n = (wv * 2 + ni) * 16 + lm;
          float v = acc3[mi][ni][r];
          if (br == 0) v = (v + bqv[ni]) * scale;
          dst[(size_t)(row0 + rl) * 128 + n] = f2bu(v);
        }
  }
  __syncthreads();
  // fourth GEMM: g (br0) / v (br1)
  stage_W(w_lds, wt_all + (size_t)((br == 0) ? 7 : 6) * 16384, tid);
  __syncthreads();
  f32x4 acc4[2][2] = {};
  gemm32(a2_lds, w_lds, lm, kg, wv, acc4);
  {
    unsigned short* dst = (br == 0) ? gsig_b : v_b;
#pragma unroll
    for (int mi = 0; mi < 2; ++mi)
#pragma unroll
      for (int ni = 0; ni < 2; ++ni)
#pragma unroll
        for (int r = 0; r < 4; ++r) {
          const int rl = mi * 16 + kg * 4 + r;
          const int n = (wv * 2 + ni) * 16 + lm;
          float v = acc4[mi][ni][r];
          if (br == 0) v = sigm(v);
          dst[(size_t)(row0 + rl) * 128 + n] = f2bu(v);
        }
  }
}

// ------------------------------------------------------------------
// K3: fused attention + output projection. One block per 32-query tile,
// 512 threads: 2 passes x 2 heads in parallel (256 threads/head, verbatim
// round-4 attn math), then o@Wo with gs gating.
// ------------------------------------------------------------------
__global__ __launch_bounds__(512) void attn_out_kernel(
    const unsigned short* __restrict__ q_b, const unsigned short* __restrict__ k_b,
    const unsigned short* __restrict__ v_b, const unsigned short* __restrict__ gsig_b,
    const unsigned short* __restrict__ gs_b, const unsigned short* __restrict__ bias_h,
    const unsigned short* __restrict__ wt_all, float* __restrict__ out)
{
  __shared__ unsigned short kw[16384];            // pass: K (2 heads); final: Wo
  __shared__ unsigned short vt[2][32 * 128];
  __shared__ unsigned short p_lds[2][32 * 128];
  __shared__ unsigned short q_lds[2][32 * 64];
  __shared__ unsigned short bias_lds[2][32 * 136];
  __shared__ float mxlds[2][4][32];
  __shared__ float smlds[2][4][32];
  __shared__ f32x4 op[2][16][64];
  __shared__ unsigned short o_lds[32 * 128];

  const int tid = threadIdx.x;
  const int b = blockIdx.x;
  const int j0 = b * 32 - 48;
  const int t = tid & 255;
  const int hh = tid >> 8;
  const int l = t & 63, wv = t >> 6;
  const int lm = l & 15, kg = l >> 4;

  for (int hp = 0; hp < 2; ++hp) {
    const int h = hp * 2 + hh;
    unsigned short* k_lds = kw + hh * 8192;
    { // Q stage
      const int r = t >> 3, c0 = (t & 7) << 2;
      ushort4 v = *(const ushort4*)(q_b + (size_t)(b * 32 + r) * 128 + h * 32 + c0);
      *(ushort4*)&q_lds[hh][r * 64 + (c0 ^ ((r & 7) << 3))] = v;
    }
    { // bias stage
      const int r = t >> 3, c0 = (t & 7) << 4;
      const uint4* g = (const uint4*)(bias_h + (size_t)h * (NTOK * 128) + (size_t)(b * 32 + r) * 128 + c0);
      uint4 v0 = g[0], v1 = g[1];
      *(uint4*)&bias_lds[hh][r * 136 + c0] = v0;
      *(uint4*)&bias_lds[hh][r * 136 + c0 + 8] = v1;
    }
    { // K + V stage (V transposed)
      const int jw = t >> 1, cb = (t & 1) << 4;
      const int j = j0 + jw;
      uint4 kv0 = {0,0,0,0}, kv1 = {0,0,0,0}, vv0 = {0,0,0,0}, vv1 = {0,0,0,0};
      if (j >= 0 && j < NTOK) {
        const uint4* gk = (const uint4*)(k_b + (size_t)j * 128 + h * 32 + cb);
        kv0 = gk[0]; kv1 = gk[1];
        const uint4* gv = (const uint4*)(v_b + (size_t)j * 128 + h * 32 + cb);
        vv0 = gv[0]; vv1 = gv[1];
      }
      const int xk = (jw & 7) << 3;
      *(uint4*)&k_lds[jw * 64 + (cb ^ xk)] = kv0;
      *(uint4*)&k_lds[jw * 64 + ((cb + 8) ^ xk)] = kv1;
      unsigned short tmp[16];
      __builtin_memcpy(tmp, &vv0, 16);
      __builtin_memcpy(tmp + 8, &vv1, 16);
#pragma unroll
      for (int i2 = 0; i2 < 16; ++i2) {
        const int c = cb + i2;
        vt[hh][c * 128 + ((jw & 7) | ((jw & 120) ^ ((c & 7) << 3)))] = tmp[i2];
      }
    }
    __syncthreads();

    // QK^T
    f32x4 sc[2][2] = {};
    {
      const int xa = (lm & 7) << 3;
      short8_t aq[2], bk[2];
#pragma unroll
      for (int mi = 0; mi < 2; ++mi)
        aq[mi] = *(const short8_t*)&q_lds[hh][(mi * 16 + lm) * 64 + ((kg * 8) ^ xa)];
#pragma unroll
      for (int ni = 0; ni < 2; ++ni) {
        const int key = (wv * 2 + ni) * 16 + lm;
        bk[ni] = *(const short8_t*)&k_lds[key * 64 + ((kg * 8) ^ ((key & 7) << 3))];
      }
#pragma unroll
      for (int mi = 0; mi < 2; ++mi)
#pragma unroll
        for (int ni = 0; ni < 2; ++ni)
          sc[mi][ni] = __builtin_amdgcn_mfma_f32_16x16x32_bf16(aq[mi], bk[ni], sc[mi][ni], 0, 0, 0);
    }
    float sv[2][2][4];
#pragma unroll
    for (int mi = 0; mi < 2; ++mi)
#pragma unroll
      for (int ni = 0; ni < 2; ++ni)
#pragma unroll
        for (int r = 0; r < 4; ++r) {
          const int q = mi * 16 + kg * 4 + r;
          const int key = (wv * 2 + ni) * 16 + lm;
          sv[mi][ni][r] = sc[mi][ni][r] + bu2f(bias_lds[hh][q * 136 + key]);
        }
#pragma unroll
    for (int mi = 0; mi < 2; ++mi)
#pragma unroll
      for (int r = 0; r < 4; ++r) {
        float m0 = fmaxf(sv[mi][0][r], sv[mi][1][r]);
#pragma unroll
        for (int msk = 1; msk < 16; msk <<= 1) m0 = fmaxf(m0, __shfl_xor(m0, msk));
        if (lm == 0) mxlds[hh][wv][mi * 16 + kg * 4 + r] = m0;
      }
    __syncthreads();
#pragma unroll
    for (int mi = 0; mi < 2; ++mi)
#pragma unroll
      for (int r = 0; r < 4; ++r) {
        const int q = mi * 16 + kg * 4 + r;
        const float m = fmaxf(fmaxf(mxlds[hh][0][q], mxlds[hh][1][q]),
                              fmaxf(mxlds[hh][2][q], mxlds[hh][3][q]));
        float s = 0.f;
#pragma unroll
        for (int ni = 0; ni < 2; ++ni) {
          const float e = __expf(sv[mi][ni][r] - m);
          const int key = (wv * 2 + ni) * 16 + lm;
          p_lds[hh][q * 128 + ((key & 7) | ((key & 120) ^ ((q & 7) << 3)))] = f2bu(e);
          s += e;
        }
#pragma unroll
        for (int msk = 1; msk < 16; msk <<= 1) s += __shfl_xor(s, msk);
        if (lm == 0) smlds[hh][wv][q] = s;
      }
    // PV: wave-local 32 keys
    f32x4 oacc[2][2] = {};
    {
      const int key0 = wv * 32 + kg * 8;
      short8_t pa[2], vbf[2];
#pragma unroll
      for (int mi = 0; mi < 2; ++mi) {
        const int q = mi * 16 + lm;
        pa[mi] = *(const short8_t*)&p_lds[hh][q * 128 + (key0 ^ ((q & 7) << 3))];
      }
#pragma unroll
      for (int ct = 0; ct < 2; ++ct) {
        const int c = ct * 16 + lm;
        vbf[ct] = *(const short8_t*)&vt[hh][c * 128 + (key0 ^ ((c & 7) << 3))];
      }
#pragma unroll
      for (int mi = 0; mi < 2; ++mi)
#pragma unroll
        for (int ct = 0; ct < 2; ++ct)
          oacc[mi][ct] = __builtin_amdgcn_mfma_f32_16x16x32_bf16(pa[mi], vbf[ct], oacc[mi][ct], 0, 0, 0);
    }
#pragma unroll
    for (int mi = 0; mi < 2; ++mi)
#pragma unroll
      for (int ct = 0; ct < 2; ++ct)
        op[hh][wv * 4 + mi * 2 + ct][l] = oacc[mi][ct];
    __syncthreads();
    { // reduce partials + gsig gate -> o_lds (swizzled bf16)
      const int q = t >> 3, c0 = (t & 7) << 2;
      const int mt = q >> 4, g = (q >> 2) & 3, r = q & 3;
      const float tot = smlds[hh][0][q] + smlds[hh][1][q] + smlds[hh][2][q] + smlds[hh][3][q];
      const float inv = 1.f / tot;
      ushort4 gg = *(const ushort4*)(gsig_b + (size_t)(b * 32 + q) * 128 + h * 32 + c0);
      unsigned short gga[4] = {gg.x, gg.y, gg.z, gg.w};
#pragma unroll
      for (int i2 = 0; i2 < 4; ++i2) {
        const int c = c0 + i2;
        const int ct = c >> 4, lane2 = g * 16 + (c & 15);
        float s = 0.f;
#pragma unroll
        for (int w2 = 0; w2 < 4; ++w2)
          s += ((const float*)&op[hh][w2 * 4 + mt * 2 + ct][lane2])[r];
        const int gcol = h * 32 + c;
        o_lds[q * 128 + (gcol ^ ((q & 7) << 3))] = f2bu(s * inv * bu2f(gga[i2]));
      }
    }
    __syncthreads();
  }

  // stage Wo into kw (512 threads: 64B each)
  {
    const int n = tid >> 2, kc = (tid & 3) << 5;
    const int x = (n & 7) << 3;
    const uint4* g = (const uint4*)(wt_all + (size_t)9 * 16384 + (size_t)n * 128 + kc);
#pragma unroll
    for (int i = 0; i < 4; ++i) {
      uint4 v = g[i];
      *(uint4*)&kw[n * 128 + ((kc + i * 8) ^ x)] = v;
    }
  }
  __syncthreads();
  // out = gs * (o @ Wo): 8 waves = 2 M-halves x 4 N-quarters
  {
    const int wid = tid >> 6, lane = tid & 63;
    const int lm8 = lane & 15, kg8 = lane >> 4;
    const int mh = wid >> 2, nq = wid & 3;
    f32x4 acc[2] = {};
    const int xa = (lm8 & 7) << 3;
#pragma unroll
    for (int ks = 0; ks < 4; ++ks) {
      const int ko = ks * 32 + kg8 * 8;
      short8_t av = *(const short8_t*)&o_lds[(mh * 16 + lm8) * 128 + (ko ^ xa)];
#pragma unroll
      for (int ni = 0; ni < 2; ++ni) {
        const int n = nq * 32 + ni * 16 + lm8;
        short8_t bv = *(const short8_t*)&kw[n * 128 + (ko ^ ((n & 7) << 3))];
        acc[ni] = __builtin_amdgcn_mfma_f32_16x16x32_bf16(av, bv, acc[ni], 0, 0, 0);
      }
    }
#pragma unroll
    for (int ni = 0; ni < 2; ++ni)
#pragma unroll
      for (int r = 0; r < 4; ++r) {
        const int row = mh * 16 + kg8 * 4 + r;
        const int n = nq * 32 + ni * 16 + lm8;
        const float gsv = bu2f(gs_b[(size_t)(b * 32 + row) * 128 + n]);
        out[(size_t)(b * 32 + row) * 128 + n] = acc[ni][r] * gsv;
      }
  }
}

extern "C" void kernel_launch(void* const* d_in, const int* in_sizes, int n_in,
                              void* d_out, int out_size, void* d_ws, size_t ws_size,
                              hipStream_t stream) {
  const float* act     = (const float*)d_in[0];
  const float* pair    = (const float*)d_in[1];
  const float* cond    = (const float*)d_in[2];
  const float* lns_q   = (const float*)d_in[4];
  const float* Wgate_q = (const float*)d_in[5];
  const float* bgate_q = (const float*)d_in[6];
  const float* Wskip_q = (const float*)d_in[7];
  const float* lns_k   = (const float*)d_in[8];
  const float* Wgate_k = (const float*)d_in[9];
  const float* bgate_k = (const float*)d_in[10];
  const float* Wskip_k = (const float*)d_in[11];
  const float* lnz_w   = (const float*)d_in[12];
  const float* Wq      = (const float*)d_in[13];
  const float* bq      = (const float*)d_in[14];
  const float* Wk      = (const float*)d_in[15];
  const float* Wv      = (const float*)d_in[16];
  const float* Wg      = (const float*)d_in[17];
  const float* Wb      = (const float*)d_in[18];
  const float* Wo      = (const float*)d_in[19];
  const float* Wgs     = (const float*)d_in[20];
  const float* bgs     = (const float*)d_in[21];
  float* out           = (float*)d_out;

  unsigned short* ws = (unsigned short*)d_ws;
  unsigned short* wt_all = ws;                      // 10*16384
  unsigned short* xn_b   = ws + 163840;
  unsigned short* sn_b   = ws + 425984;
  unsigned short* cond_b = ws + 688128;
  unsigned short* q_b    = ws + 950272;
  unsigned short* k_b    = ws + 1212416;
  unsigned short* v_b    = ws + 1474560;
  unsigned short* gsig_b = ws + 1736704;
  unsigned short* gs_b   = ws + 1998848;
  unsigned short* bias_h = ws + 2260992;            // 4*2048*128

  hipLaunchKernelGGL(prep_bias_kernel, dim3(1248), dim3(256), 0, stream,
                     act, cond, lns_q, lns_k,
                     Wgate_q, Wskip_q, Wgate_k, Wskip_k,
                     Wq, Wk, Wv, Wg, Wgs, Wo,
                     pair, lnz_w, Wb,
                     wt_all, xn_b, sn_b, cond_b, bias_h);
  hipLaunchKernelGGL(proj_kernel, dim3(192), dim3(256), 0, stream,
                     wt_all, xn_b, sn_b, cond_b,
                     bgate_q, bgate_k, bq, bgs,
                     q_b, k_b, v_b, gsig_b, gs_b);
  hipLaunchKernelGGL(attn_out_kernel, dim3(64), dim3(512), 0, stream,
                     q_b, k_b, v_b, gsig_b, gs_b, bias_h, wt_all, out);
}